// Round 11
// baseline (282.518 us; speedup 1.0000x reference)
//
#include <hip/hip_runtime.h>
#include <hip/hip_bf16.h>
#include <stdint.h>

typedef __attribute__((ext_vector_type(4))) float f32x4;
typedef __attribute__((ext_vector_type(8))) short short8;

__device__ __forceinline__ ushort f2b(float f) {
    union { __hip_bfloat16 h; ushort u; } c;
    c.h = __float2bfloat16(f);
    return c.u;
}

// async global->LDS, 16B per lane. LDS dest is wave-uniform; HW adds lane*16.
__device__ __forceinline__ void gload_lds16(const void* g, void* lds) {
    __builtin_amdgcn_global_load_lds((const __attribute__((address_space(1))) void*)g,
                                     (__attribute__((address_space(3))) void*)lds,
                                     16, 0, 0);
}

#define BARRIER()  asm volatile("s_barrier" ::: "memory")
#define VMCNT0()   asm volatile("s_waitcnt vmcnt(0)" ::: "memory")

// ---- fused pre-pass: x -> bf16 (y==0), w * blockscale -> bf16 (y==1) --------
__global__ void conv_both_kernel(const float* __restrict__ x, ushort* __restrict__ xb, long n8x,
                                 const float* __restrict__ w, const float* __restrict__ sinv,
                                 ushort* __restrict__ wb, int K, int nbk, long n8w) {
    long i = (long)blockIdx.x * blockDim.x + threadIdx.x;
    if (blockIdx.y == 0) {
        if (i >= n8x) return;
        const float4* xv = (const float4*)x;
        float4 v0 = xv[i * 2], v1 = xv[i * 2 + 1];
        short8 r;
        r[0] = (short)f2b(v0.x); r[1] = (short)f2b(v0.y); r[2] = (short)f2b(v0.z); r[3] = (short)f2b(v0.w);
        r[4] = (short)f2b(v1.x); r[5] = (short)f2b(v1.y); r[6] = (short)f2b(v1.z); r[7] = (short)f2b(v1.w);
        *(short8*)&xb[i * 8] = r;
    } else {
        if (i >= n8w) return;
        long e = i * 8;
        int o, c;
        if (K == 4096) { o = (int)(e >> 12); c = (int)(e & 4095); }
        else { o = (int)(e / K); c = (int)(e - (long)o * K); }
        const float s = sinv[(o >> 7) * nbk + (c >> 7)];
        const float4* wv = (const float4*)(w + e);
        float4 v0 = wv[0], v1 = wv[1];
        short8 r;
        r[0] = (short)f2b(v0.x * s); r[1] = (short)f2b(v0.y * s); r[2] = (short)f2b(v0.z * s); r[3] = (short)f2b(v0.w * s);
        r[4] = (short)f2b(v1.x * s); r[5] = (short)f2b(v1.y * s); r[6] = (short)f2b(v1.z * s); r[7] = (short)f2b(v1.w * s);
        *(short8*)&wb[e] = r;
    }
}

// ---- main GEMM: 256x256 tile, BK=64, 8 waves (2Mx4N) ------------------------
// Cross-phase pre-read pipeline: P3 of tile t pre-reads tile t+1's P0
// fragments (aCur/bCur, carried registers) from the freshly-drained buffer
// tb, so EVERY phase's MFMA cluster is immediately issueable after its
// barrier. Drain vmcnt(0) at P2-end (before P3's barrier) = exact
// visibility condition for the P3 pre-read. Stages(t+1->tb) at P0/P1.
__global__ __launch_bounds__(512, 2)
void gemm256_kernel(const ushort* __restrict__ A, const ushort* __restrict__ Bm,
                    const float* __restrict__ bias, float* __restrict__ C,
                    int M, int N, int K) {
    __shared__ alignas(16) short sm[2][32768];   // [buf][ A:16384 shorts | B:16384 shorts ]

    const int tid  = threadIdx.x;
    const int lane = tid & 63;
    const int wid  = tid >> 6;
    const int wr   = wid >> 2;          // 0..1  -> 128-row slice of C
    const int wc   = wid & 3;           // 0..3  -> 64-col slice of C
    const int nbn  = N >> 8;

    // XCD-aware bijective swizzle (launcher guarantees gridDim.x % 8 == 0)
    const int nwg = gridDim.x;
    const int swz = (blockIdx.x & 7) * (nwg >> 3) + (blockIdx.x >> 3);
    const int bm  = swz / nbn;
    const int bn  = swz % nbn;

    const short* gA = (const short*)A + (size_t)bm * 256 * K;
    const short* gB = (const short*)Bm + (size_t)bn * 256 * K;

    // staging: unit U = 64 rows x 64 cols (8KB); thread row U*64+wid*8+(lane>>3),
    // global col chunk pre-swizzled so linear LDS write == XOR-swizzled layout.
    const int srow = wid * 8 + (lane >> 3);
    const int scol = ((lane & 7) ^ (lane >> 3)) << 3;

    auto STAGE_A = [&](int U, int kt, int buf) {
        const short* src = gA + (size_t)(U * 64 + srow) * K + kt * 64 + scol;
        gload_lds16(src, &sm[buf][U * 4096 + wid * 512]);
    };
    auto STAGE_B = [&](int U, int kt, int buf) {
        const short* src = gB + (size_t)(U * 64 + srow) * K + kt * 64 + scol;
        gload_lds16(src, &sm[buf][16384 + U * 4096 + wid * 512]);
    };

    // fragment reads (swizzled): row*64 + ((chunk*8) ^ ((row&7)*8))
    auto LD_A = [&](const short* Ab, int mh, int kk, short8 (&a)[4]) {
#pragma unroll
        for (int m = 0; m < 4; ++m) {
            int row = wr * 128 + mh * 64 + m * 16 + (lane & 15);
            a[m] = *(const short8*)&Ab[row * 64 + ((kk * 32 + (lane >> 4) * 8) ^ ((lane & 7) << 3))];
        }
    };
    auto LD_B = [&](const short* Bb, int kk, short8 (&b)[4]) {
#pragma unroll
        for (int n = 0; n < 4; ++n) {
            int row = wc * 64 + n * 16 + (lane & 15);
            b[n] = *(const short8*)&Bb[row * 64 + ((kk * 32 + (lane >> 4) * 8) ^ ((lane & 7) << 3))];
        }
    };

    f32x4 acc[8][4] = {};

    auto MFMA_H = [&](int off, short8 (&af)[4], short8 (&bf)[4], int m0, int m1) {
#pragma unroll
        for (int m = m0; m < m1; ++m)
#pragma unroll
            for (int n = 0; n < 4; ++n)
                acc[off + m][n] = __builtin_amdgcn_mfma_f32_16x16x32_bf16(af[m], bf[n], acc[off + m][n], 0, 0, 0);
    };

    const int nkt = K >> 6;   // >= 2 and even (launcher enforces K % 128 == 0)

    short8 aCur[4], bCur[4];  // carried across K-tiles: next tile's P0 fragments

    auto KSTEP = [&](int t) {
        const int b  = t & 1;
        const int tb = b ^ 1;
        const short* Ab  = &sm[b][0];
        const short* Bb  = &sm[b][16384];
        const short* AbN = &sm[tb][0];
        const short* BbN = &sm[tb][16384];
        const int tn = (t + 1 < nkt) ? t + 1 : nkt - 1;   // clamped tail: writes tb, pre-read unused after loop

        short8 aB[4], aC[4], aD[4], bB[4];

        // ---- P0: MFMA(aCur,bCur) [pre-read last P3]; embedded LD aB; stage 4 ----
        BARRIER();
        __builtin_amdgcn_s_setprio(1);
        MFMA_H(0, aCur, bCur, 0, 2);
        LD_A(Ab, 1, 0, aB);
        MFMA_H(0, aCur, bCur, 2, 4);
        __builtin_amdgcn_s_setprio(0);
        STAGE_B(0, tn, tb); STAGE_B(1, tn, tb);
        STAGE_A(0, tn, tb); STAGE_A(2, tn, tb);

        // ---- P1: MFMA(aB,bCur); embedded LD aC, bB; stage 4 ----
        BARRIER();
        __builtin_amdgcn_s_setprio(1);
        MFMA_H(4, aB, bCur, 0, 2);
        LD_A(Ab, 0, 1, aC);
        LD_B(Bb, 1, bB);
        MFMA_H(4, aB, bCur, 2, 4);
        __builtin_amdgcn_s_setprio(0);
        STAGE_A(1, tn, tb); STAGE_A(3, tn, tb);
        STAGE_B(2, tn, tb); STAGE_B(3, tn, tb);

        // ---- P2: MFMA(aC,bB); embedded LD aD; drain t+1 stages BEFORE P3's barrier ----
        BARRIER();
        __builtin_amdgcn_s_setprio(1);
        MFMA_H(0, aC, bB, 0, 2);
        LD_A(Ab, 1, 1, aD);
        MFMA_H(0, aC, bB, 2, 4);
        __builtin_amdgcn_s_setprio(0);
        VMCNT0();

        // ---- P3: MFMA(aD,bB); embedded pre-read of tile t+1's P0 frags from tb ----
        BARRIER();
        __builtin_amdgcn_s_setprio(1);
        MFMA_H(4, aD, bB, 0, 2);
        LD_A(AbN, 0, 0, aCur);
        LD_B(BbN, 0, bCur);
        MFMA_H(4, aD, bB, 2, 4);
        __builtin_amdgcn_s_setprio(0);
    };

    // ---- prologue: tile0 -> buf0, drain, pre-read P0 frags ----
    {
        STAGE_B(0, 0, 0); STAGE_B(1, 0, 0);
        STAGE_A(0, 0, 0); STAGE_A(2, 0, 0);
        STAGE_A(1, 0, 0); STAGE_A(3, 0, 0);
        STAGE_B(2, 0, 0); STAGE_B(3, 0, 0);
        VMCNT0();
        BARRIER();
        LD_A(&sm[0][0], 0, 0, aCur);
        LD_B(&sm[0][16384], 0, bCur);
    }

    // 2 K-tiles per body: 8 phases visible to the scheduler
    for (int t = 0; t < nkt; t += 2) {
        KSTEP(t);
        KSTEP(t + 1);
    }

    // ---- epilogue: C = acc + bias (fp32); regs only, no barrier needed ----
    const int r0 = bm * 256 + wr * 128 + (lane >> 4) * 4;
    const int c0 = bn * 256 + wc * 64 + (lane & 15);
#pragma unroll
    for (int n = 0; n < 4; ++n) {
        float bv = bias[c0 + n * 16];
#pragma unroll
        for (int m = 0; m < 8; ++m) {
#pragma unroll
            for (int r = 0; r < 4; ++r) {
                C[(size_t)(r0 + m * 16 + r) * N + (c0 + n * 16)] = acc[m][n][r] + bv;
            }
        }
    }
}

// ---- fallback (shape-generic, slow but correct) -----------------------------
__global__ void fallback_gemm(const float* __restrict__ x, const float* __restrict__ w,
                              const float* __restrict__ sinv, const float* __restrict__ bias,
                              float* __restrict__ out, int M, int N, int K) {
    int n = blockIdx.x * 64 + (threadIdx.x & 63);
    int m = blockIdx.y * 4 + (threadIdx.x >> 6);
    if (m >= M || n >= N) return;
    const int nbk = K >> 7;
    float acc = 0.f;
    for (int k = 0; k < K; ++k)
        acc += x[(size_t)m * K + k] * w[(size_t)n * K + k] * sinv[(n >> 7) * nbk + (k >> 7)];
    out[(size_t)m * N + n] = acc + bias[n];
}

extern "C" void kernel_launch(void* const* d_in, const int* in_sizes, int n_in,
                              void* d_out, int out_size, void* d_ws, size_t ws_size,
                              hipStream_t stream) {
    const float* x    = (const float*)d_in[0];
    const float* w    = (const float*)d_in[1];
    const float* sinv = (const float*)d_in[2];
    const float* bias = (const float*)d_in[3];
    float* out        = (float*)d_out;

    const int O = in_sizes[3];                  // 4096
    const int K = in_sizes[1] / O;              // 4096
    const int M = (int)((long)in_sizes[0] / K); // B*S = 4096
    const int N = O;

    const size_t need = ((size_t)M * K + (size_t)N * K) * sizeof(ushort);
    const int nwg = (M / 256) * (N / 256);
    const bool ok = ws_size >= need && (M % 256 == 0) && (N % 256 == 0) &&
                    (K % 128 == 0) && (nwg % 8 == 0) && ((long)M * K % 2048 == 0) &&
                    (K % 2048 == 0);
    if (ok) {
        ushort* xb = (ushort*)d_ws;
        ushort* wb = xb + (size_t)M * K;
        long n8x = (long)M * K / 8;
        long n8w = (long)N * K / 8;
        long n8m = (n8x > n8w) ? n8x : n8w;
        dim3 cg((unsigned)((n8m + 255) / 256), 2);
        conv_both_kernel<<<cg, 256, 0, stream>>>(x, xb, n8x, w, sinv, wb, K, K >> 7, n8w);
        gemm256_kernel<<<dim3(nwg), 512, 0, stream>>>(xb, wb, bias, out, M, N, K);
    } else {
        dim3 g(N / 64, (M + 3) / 4);
        fallback_gemm<<<g, 256, 0, stream>>>(x, w, sinv, bias, out, M, N, K);
    }
}